// Round 1
// baseline (1800.542 us; speedup 1.0000x reference)
//
#include <hip/hip_runtime.h>

// Problem constants (N,C,H,W)=(4,96,96,96), half-res 48x48
#define BN_ 4
#define CC 96
#define HF 96
#define WF 96
#define HS 48
#define WS 48
#define LL 2304      // HS*WS  (context patch count, also position count)
#define K1 864       // CC*9   (3x3 patch feature dim)
#define J2 1536      // CC*16  (4x4 raw filter feature dim)
#define NEG10 (-1.0e10f)   // NEG_BIG * SOFTMAX_SCALE

__device__ __forceinline__ int Tswap(int f) { return (f % 48) * 48 + f / 48; }

// ---- im2col of 3x3 patches (pad 1) of the ::2,::2 strided slice ----
// dst[n][k][l], k = c*9 + (dy+1)*3 + (dx+1), l = i*48+j
__global__ void im2col3x3(const float* __restrict__ src, float* __restrict__ dst) {
    int idx = blockIdx.x * 256 + threadIdx.x;
    if (idx >= BN_ * K1 * LL) return;
    int l = idx % LL;
    int k = (idx / LL) % K1;
    int n = idx / (LL * K1);
    int c = k / 9;
    int r = k % 9;
    int i = l / WS + r / 3 - 1;
    int j = l % WS + r % 3 - 1;
    float v = 0.f;
    if (i >= 0 && i < HS && j >= 0 && j < WS)
        v = src[((size_t)(n * CC + c) * HF + 2 * i) * WF + 2 * j];
    dst[idx] = v;
}

// ---- inv_norm[n][l] = 1/max(||cols[:,l]||, 1e-4) ----
__global__ void calc_invnorm(const float* __restrict__ cols_t, float* __restrict__ invn) {
    int idx = blockIdx.x * 256 + threadIdx.x;
    if (idx >= BN_ * LL) return;
    int l = idx % LL, n = idx / LL;
    const float* base = cols_t + (size_t)n * K1 * LL + l;
    float ss = 0.f;
    for (int k = 0; k < K1; ++k) { float v = base[(size_t)k * LL]; ss += v * v; }
    invn[idx] = 1.f / fmaxf(sqrtf(ss), 1e-4f);
}

// ---- maskadd[n][l] = -1e10 if any mask in 3x3 half-res neighborhood ----
__global__ void calc_mask(const float* __restrict__ mask, float* __restrict__ maskadd) {
    int idx = blockIdx.x * 256 + threadIdx.x;
    if (idx >= BN_ * LL) return;
    int l = idx % LL, n = idx / LL;
    int i0 = l / WS, j0 = l % WS;
    float s = 0.f;
    for (int dy = -1; dy <= 1; ++dy)
        for (int dx = -1; dx <= 1; ++dx) {
            int i = i0 + dy, j = j0 + dx;
            if (i >= 0 && i < HS && j >= 0 && j < WS)
                s += mask[(size_t)n * HF * WF + (2 * i) * WF + 2 * j];
        }
    maskadd[idx] = (s > 0.f) ? NEG10 : 0.f;
}

// ---- TN SGEMM: C[m][nn] = sum_k A[k][m] * B[k][nn]; row strides = M / Nn ----
// 128x128 tile, 256 threads, 8x8 per thread. All dims divide evenly here.
__global__ __launch_bounds__(256) void gemm_tn(
    const float* __restrict__ A, const float* __restrict__ B, float* __restrict__ Cc,
    int M, int Nn, int Kk, size_t sA, size_t sB, size_t sC,
    const float* __restrict__ rowscale, int rs_stride)
{
    __shared__ float As[16][128];
    __shared__ float Bs[16][128];
    int bz = blockIdx.z;
    const float* Ab = A + (size_t)bz * sA;
    const float* Bb = B + (size_t)bz * sB;
    int m0 = blockIdx.y * 128, n0 = blockIdx.x * 128;
    int tid = threadIdx.x;
    int tx = tid % 16, ty = tid / 16;
    float acc[8][8] = {};
    for (int k0 = 0; k0 < Kk; k0 += 16) {
#pragma unroll
        for (int rep = 0; rep < 2; ++rep) {
            int f = tid + rep * 256;           // 512 float4 slots per operand tile
            int kk = f >> 5;
            int c4 = (f & 31) << 2;
            *reinterpret_cast<float4*>(&As[kk][c4]) =
                *reinterpret_cast<const float4*>(&Ab[(size_t)(k0 + kk) * M + m0 + c4]);
            *reinterpret_cast<float4*>(&Bs[kk][c4]) =
                *reinterpret_cast<const float4*>(&Bb[(size_t)(k0 + kk) * Nn + n0 + c4]);
        }
        __syncthreads();
#pragma unroll
        for (int kk = 0; kk < 16; ++kk) {
            float a[8], b[8];
            *reinterpret_cast<float4*>(&a[0]) = *reinterpret_cast<const float4*>(&As[kk][ty * 8]);
            *reinterpret_cast<float4*>(&a[4]) = *reinterpret_cast<const float4*>(&As[kk][ty * 8 + 4]);
            *reinterpret_cast<float4*>(&b[0]) = *reinterpret_cast<const float4*>(&Bs[kk][tx * 8]);
            *reinterpret_cast<float4*>(&b[4]) = *reinterpret_cast<const float4*>(&Bs[kk][tx * 8 + 4]);
#pragma unroll
            for (int i = 0; i < 8; ++i)
#pragma unroll
                for (int j = 0; j < 8; ++j)
                    acc[i][j] = fmaf(a[i], b[j], acc[i][j]);
        }
        __syncthreads();
    }
    float* Cb = Cc + (size_t)bz * sC;
#pragma unroll
    for (int i = 0; i < 8; ++i) {
        int m = m0 + ty * 8 + i;
        float scale = rowscale ? rowscale[bz * rs_stride + m] : 1.f;
        float4 o0, o1;
        o0.x = acc[i][0] * scale; o0.y = acc[i][1] * scale;
        o0.z = acc[i][2] * scale; o0.w = acc[i][3] * scale;
        o1.x = acc[i][4] * scale; o1.y = acc[i][5] * scale;
        o1.z = acc[i][6] * scale; o1.w = acc[i][7] * scale;
        *reinterpret_cast<float4*>(&Cb[(size_t)m * Nn + n0 + tx * 8]) = o0;
        *reinterpret_cast<float4*>(&Cb[(size_t)m * Nn + n0 + tx * 8 + 4]) = o1;
    }
}

// ---- fused double conv_eye (both flat-index diagonal convs) + mask + x10 ----
// out[l][p] = 10 * sum_{d2,d1} S[shift(l),shift(p)] + maskadd[l]
__global__ void fuse_kernel(const float* __restrict__ S, const float* __restrict__ maskadd,
                            float* __restrict__ Sf) {
    int idx = blockIdx.x * 256 + threadIdx.x;
    if (idx >= BN_ * LL * LL) return;
    int p = idx % LL;
    int l = (idx / LL) % LL;
    int n = idx / (LL * LL);
    const float* Sb = S + (size_t)n * LL * LL;
    int Tl = Tswap(l), Tp = Tswap(p);
    float acc = 0.f;
#pragma unroll
    for (int d2 = -1; d2 <= 1; ++d2) {
        int fl = Tl + d2, fp = Tp + d2;
        if (fl < 0 || fl >= LL || fp < 0 || fp >= LL) continue;
        int l2 = Tswap(fl), p2 = Tswap(fp);
#pragma unroll
        for (int d1 = -1; d1 <= 1; ++d1) {
            int l3 = l2 + d1, p3 = p2 + d1;
            if (l3 < 0 || l3 >= LL || p3 < 0 || p3 >= LL) continue;
            acc += Sb[(size_t)l3 * LL + p3];
        }
    }
    Sf[idx] = acc * 10.f + maskadd[n * LL + l];
}

// ---- softmax over l (axis with stride LL), in place; block = 32 p x 8 l-groups ----
__global__ __launch_bounds__(256) void softmax_kernel(float* __restrict__ att) {
    __shared__ float red[8][32];
    int pi = threadIdx.x & 31;
    int lg = threadIdx.x >> 5;
    int p = blockIdx.x * 32 + pi;
    int n = blockIdx.y;
    float* col = att + (size_t)n * LL * LL + p;
    float m = -3e38f;
    for (int l = lg; l < LL; l += 8) m = fmaxf(m, col[(size_t)l * LL]);
    red[lg][pi] = m;
    __syncthreads();
    if (lg == 0) {
#pragma unroll
        for (int q = 1; q < 8; ++q) m = fmaxf(m, red[q][pi]);
        red[0][pi] = m;
    }
    __syncthreads();
    m = red[0][pi];
    __syncthreads();
    float s = 0.f;
    for (int l = lg; l < LL; l += 8) s += __expf(col[(size_t)l * LL] - m);
    red[lg][pi] = s;
    __syncthreads();
    if (lg == 0) {
#pragma unroll
        for (int q = 1; q < 8; ++q) s += red[q][pi];
        red[0][pi] = 1.f / s;
    }
    __syncthreads();
    float inv = red[0][pi];
    for (int l = lg; l < LL; l += 8)
        col[(size_t)l * LL] = __expf(col[(size_t)l * LL] - m) * inv;
}

// ---- raw filter im2col: RF[n][l][c*16+ky*4+kx] = context[n,c,2iu+ky-1,2ju+kx-1] ----
__global__ void im2col_rf(const float* __restrict__ context, float* __restrict__ RF) {
    int idx = blockIdx.x * 256 + threadIdx.x;
    if (idx >= BN_ * LL * J2) return;
    int j = idx % J2;
    int l = (idx / J2) % LL;
    int n = idx / (J2 * LL);
    int c = j >> 4;
    int ky = (j >> 2) & 3, kx = j & 3;
    int y = 2 * (l / WS) + ky - 1;
    int x = 2 * (l % WS) + kx - 1;
    float v = 0.f;
    if (y >= 0 && y < HF && x >= 0 && x < WF)
        v = context[((size_t)(n * CC + c) * HF + y) * WF + x];
    RF[idx] = v;
}

// ---- col2im (transposed-conv scatter gathered at output) + overlap division ----
__global__ void col2im_kernel(const float* __restrict__ G, float* __restrict__ out) {
    int idx = blockIdx.x * 256 + threadIdx.x;
    if (idx >= BN_ * CC * HF * WF) return;
    int x = idx % WF;
    int y = (idx / WF) % HF;
    int c = (idx / (WF * HF)) % CC;
    int n = idx / (WF * HF * CC);
    const float* Gb = G + (size_t)n * LL * J2;
    float acc = 0.f;
#pragma unroll
    for (int ky = 0; ky < 4; ++ky) {
        int ynum = y + 1 - ky;
        if (ynum & 1) continue;
        int iy = ynum >> 1;
        if (iy < 0 || iy >= HS) continue;
#pragma unroll
        for (int kx = 0; kx < 4; ++kx) {
            int xnum = x + 1 - kx;
            if (xnum & 1) continue;
            int ix = xnum >> 1;
            if (ix < 0 || ix >= WS) continue;
            acc += Gb[(size_t)(iy * WS + ix) * J2 + c * 16 + ky * 4 + kx];
        }
    }
    float cy = (y == 0 || y == HF - 1) ? 1.f : 2.f;
    float cx = (x == 0 || x == WF - 1) ? 1.f : 2.f;
    out[idx] = acc / (cy * cx);
}

extern "C" void kernel_launch(void* const* d_in, const int* in_sizes, int n_in,
                              void* d_out, int out_size, void* d_ws, size_t ws_size,
                              hipStream_t stream) {
    const float* x       = (const float*)d_in[0];
    const float* context = (const float*)d_in[1];
    const float* mask    = (const float*)d_in[2];
    float* out = (float*)d_out;                                  // [4][96][96][96]
    float* att = out + (size_t)BN_ * CC * HF * WF;               // [4][2304][2304] == att_score

    // workspace layout (floats); overlays: RF reuses cols_t+xp_t, G reuses S.
    // requires ws_size >= 37,177,344 * 4 B ~= 142 MiB
    float* ws = (float*)d_ws;
    float* cols_t  = ws;                               // [4][864][2304]
    float* xp_t    = ws + (size_t)BN_ * K1 * LL;       // [4][864][2304]
    float* RF      = ws;                               // [4][2304][1536] (after GEMM1)
    float* invn    = ws + (size_t)2 * BN_ * K1 * LL;   // [4][2304]
    float* maskadd = invn + BN_ * LL;                  // [4][2304]
    float* S       = maskadd + BN_ * LL;               // [4][2304][2304]
    float* G       = S;                                // [4][2304][1536] (after fuse)

    int nIm = BN_ * K1 * LL;
    im2col3x3<<<nIm / 256, 256, 0, stream>>>(context, cols_t);
    im2col3x3<<<nIm / 256, 256, 0, stream>>>(x, xp_t);
    calc_invnorm<<<(BN_ * LL + 255) / 256, 256, 0, stream>>>(cols_t, invn);
    calc_mask<<<(BN_ * LL + 255) / 256, 256, 0, stream>>>(mask, maskadd);

    // GEMM1: S[l][p] = invn[l] * sum_k cols_t[k][l] * xp_t[k][p]
    dim3 g1(LL / 128, LL / 128, BN_);
    gemm_tn<<<g1, 256, 0, stream>>>(cols_t, xp_t, S, LL, LL, K1,
                                    (size_t)K1 * LL, (size_t)K1 * LL, (size_t)LL * LL,
                                    invn, LL);

    // fuse (both conv_eye passes) + mask + softmax scale, written into d_out att region
    fuse_kernel<<<(BN_ * LL * LL) / 256, 256, 0, stream>>>(S, maskadd, att);

    // softmax over l, in place in d_out att region
    softmax_kernel<<<dim3(LL / 32, BN_), 256, 0, stream>>>(att);

    // raw filters
    im2col_rf<<<(BN_ * LL * J2) / 256, 256, 0, stream>>>(context, RF);

    // GEMM2: G[p][j] = sum_l att[l][p] * RF[l][j]
    dim3 g2(J2 / 128, LL / 128, BN_);
    gemm_tn<<<g2, 256, 0, stream>>>(att, RF, G, LL, J2, LL,
                                    (size_t)LL * LL, (size_t)LL * J2, (size_t)LL * J2,
                                    nullptr, 0);

    // scatter to output with overlap normalization
    col2im_kernel<<<(BN_ * CC * HF * WF) / 256, 256, 0, stream>>>(G, out);
}

// Round 2
// 916.490 us; speedup vs baseline: 1.9646x; 1.9646x over previous
//
#include <hip/hip_runtime.h>
#include <stdint.h>

// Problem constants (N,C,H,W)=(4,96,96,96), half-res 48x48
#define BN_ 4
#define CC 96
#define HF 96
#define WF 96
#define HS 48
#define WS 48
#define LL 2304      // HS*WS
#define K1 864       // CC*9  (3x3 patch feature dim)
#define J2 1536      // CC*16 (4x4 raw filter feature dim)
#define NEG10 (-1.0e10f)

typedef __attribute__((ext_vector_type(8))) short short8v;
typedef __attribute__((ext_vector_type(4))) float float4v;

__device__ __forceinline__ int Tswap(int f) { return (f % 48) * 48 + f / 48; }

__device__ __forceinline__ unsigned short f2bf(float f) {
    union { float f; uint32_t u; } v; v.f = f;
    uint32_t u = v.u;
    uint32_t r = (u + 0x7fffu + ((u >> 16) & 1u)) >> 16;
    return (unsigned short)r;
}
__device__ __forceinline__ float bf2f(unsigned short h) {
    union { uint32_t u; float f; } v; v.u = ((uint32_t)h) << 16;
    return v.f;
}

typedef const __attribute__((address_space(1))) uint32_t* gas_ptr;
typedef __attribute__((address_space(3))) uint32_t* las_ptr;
__device__ __forceinline__ void gload16(const void* g, void* l) {
    __builtin_amdgcn_global_load_lds((gas_ptr)g, (las_ptr)l, 16, 0, 0);
}

// ---- channel-sum-of-squares of strided context: ssum[n][i][j] ----
__global__ void ssum_kernel(const float* __restrict__ ctx, float* __restrict__ ssum) {
    int idx = blockIdx.x * 256 + threadIdx.x;
    if (idx >= BN_ * HS * WS) return;
    int j = idx % WS, i = (idx / WS) % HS, n = idx / (WS * HS);
    float s = 0.f;
    for (int c = 0; c < CC; ++c) {
        float v = ctx[((size_t)(n * CC + c) * HF + 2 * i) * WF + 2 * j];
        s += v * v;
    }
    ssum[idx] = s;
}

// ---- invn[n][l] = 1/max(sqrt(sum 3x3 ssum),1e-4) ----
__global__ void invn_kernel(const float* __restrict__ ssum, float* __restrict__ invn) {
    int idx = blockIdx.x * 256 + threadIdx.x;
    if (idx >= BN_ * LL) return;
    int l = idx % LL, n = idx / LL;
    int i0 = l / WS, j0 = l % WS;
    float s = 0.f;
    for (int dy = -1; dy <= 1; ++dy)
        for (int dx = -1; dx <= 1; ++dx) {
            int i = i0 + dy, j = j0 + dx;
            if (i >= 0 && i < HS && j >= 0 && j < WS)
                s += ssum[(n * HS + i) * WS + j];
        }
    invn[idx] = 1.f / fmaxf(sqrtf(s), 1e-4f);
}

// ---- maskadd[n][l] ----
__global__ void mask_kernel(const float* __restrict__ mask, float* __restrict__ maskadd) {
    int idx = blockIdx.x * 256 + threadIdx.x;
    if (idx >= BN_ * LL) return;
    int l = idx % LL, n = idx / LL;
    int i0 = l / WS, j0 = l % WS;
    float s = 0.f;
    for (int dy = -1; dy <= 1; ++dy)
        for (int dx = -1; dx <= 1; ++dx) {
            int i = i0 + dy, j = j0 + dx;
            if (i >= 0 && i < HS && j >= 0 && j < WS)
                s += mask[(size_t)n * HF * WF + (2 * i) * WF + 2 * j];
        }
    maskadd[idx] = (s > 0.f) ? NEG10 : 0.f;
}

// ---- im2col 3x3 (pad 1) of ::2 slice + bf16 hi/lo split; dst [n][l][864] k-major ----
// scale==nullptr: plain; else multiply by scale[n*LL+l] (cols normalization)
__global__ void im2col_split(const float* __restrict__ src, const float* __restrict__ scale,
                             unsigned short* __restrict__ hi, unsigned short* __restrict__ lo) {
    int idx = blockIdx.x * 256 + threadIdx.x;
    if (idx >= BN_ * LL * K1) return;
    int k = idx % K1;
    int l = (idx / K1) % LL;
    int n = idx / (K1 * LL);
    int c = k / 9, r = k % 9;
    int i = l / WS + r / 3 - 1;
    int j = l % WS + r % 3 - 1;
    float v = 0.f;
    if (i >= 0 && i < HS && j >= 0 && j < WS)
        v = src[((size_t)(n * CC + c) * HF + 2 * i) * WF + 2 * j];
    if (scale) v *= scale[n * LL + l];
    unsigned short h = f2bf(v);
    hi[idx] = h;
    lo[idx] = f2bf(v - bf2f(h));
}

// ---- raw filter, transposed + split: RF[n][j][l] (k=l contiguous) ----
__global__ void rf_split(const float* __restrict__ ctx,
                         unsigned short* __restrict__ hi, unsigned short* __restrict__ lo) {
    int idx = blockIdx.x * 256 + threadIdx.x;
    if (idx >= BN_ * J2 * LL) return;
    int l = idx % LL;
    int j = (idx / LL) % J2;
    int n = idx / (LL * J2);
    int c = j >> 4, ky = (j >> 2) & 3, kx = j & 3;
    int y = 2 * (l / WS) + ky - 1;
    int x = 2 * (l % WS) + kx - 1;
    float v = 0.f;
    if (y >= 0 && y < HF && x >= 0 && x < WF)
        v = ctx[((size_t)(n * CC + c) * HF + y) * WF + x];
    unsigned short h = f2bf(v);
    hi[idx] = h;
    lo[idx] = f2bf(v - bf2f(h));
}

// ---- split-bf16 MFMA GEMM: C[m][n] = sum_k A[m][k]*B[n][k] via Ah*Bh+Ah*Bl+Al*Bh ----
// A: [M][K] k-major bf16 hi/lo, B: [N][K] k-major bf16 hi/lo. 128x128 tile, BK=32.
// SCAT=false: write fp32 C. SCAT=true: col2im atomic scatter into out (GEMM2).
template <bool SCAT>
__global__ __launch_bounds__(256, 3) void gemm_split(
    const unsigned short* __restrict__ Ah_, const unsigned short* __restrict__ Al_,
    const unsigned short* __restrict__ Bh_, const unsigned short* __restrict__ Bl_,
    float* __restrict__ Cout, int M_, int N_, int K_)
{
    __shared__ unsigned short lds[4][128][32];   // Ah, Al, Bh, Bl tiles
    const int bz = blockIdx.z;
    const int m0 = blockIdx.y * 128, n0 = blockIdx.x * 128;
    const int t = threadIdx.x;

    const size_t sA = (size_t)M_ * K_, sB = (size_t)N_ * K_;
    const unsigned short* Ah = Ah_ + (size_t)bz * sA;
    const unsigned short* Al = Al_ + (size_t)bz * sA;
    const unsigned short* Bh = Bh_ + (size_t)bz * sB;
    const unsigned short* Bl = Bl_ + (size_t)bz * sB;

    // staging geometry: thread t covers LDS row rloc (tile-local), 16B slot sst.
    // XOR swizzle: phys slot sst holds logical k-group kg = sst ^ ((rloc>>1)&3).
    const int rloc = t >> 2;
    const int sst = t & 3;
    const int kg = sst ^ ((rloc >> 1) & 3);
    const size_t offA0 = (size_t)(m0 + rloc) * K_ + kg * 8;
    const size_t offA1 = (size_t)(m0 + 64 + rloc) * K_ + kg * 8;
    const size_t offB0 = (size_t)(n0 + rloc) * K_ + kg * 8;
    const size_t offB1 = (size_t)(n0 + 64 + rloc) * K_ + kg * 8;
    const unsigned short* gp0 = Ah + offA0;
    const unsigned short* gp1 = Ah + offA1;
    const unsigned short* gp2 = Al + offA0;
    const unsigned short* gp3 = Al + offA1;
    const unsigned short* gp4 = Bh + offB0;
    const unsigned short* gp5 = Bh + offB1;
    const unsigned short* gp6 = Bl + offB0;
    const unsigned short* gp7 = Bl + offB1;
    unsigned short* lp0 = &lds[0][rloc][sst * 8];
    unsigned short* lp1 = &lds[0][64 + rloc][sst * 8];
    unsigned short* lp2 = &lds[1][rloc][sst * 8];
    unsigned short* lp3 = &lds[1][64 + rloc][sst * 8];
    unsigned short* lp4 = &lds[2][rloc][sst * 8];
    unsigned short* lp5 = &lds[2][64 + rloc][sst * 8];
    unsigned short* lp6 = &lds[3][rloc][sst * 8];
    unsigned short* lp7 = &lds[3][64 + rloc][sst * 8];

    const int lane = t & 63;
    const int w = t >> 6, wr = w >> 1, wc = w & 1;
    const int lr = lane & 15, lg = lane >> 4;

    float4v acc[4][4] = {};

    for (int kt = 0; kt < K_; kt += 32) {
        __syncthreads();
        gload16(gp0, lp0); gload16(gp1, lp1);
        gload16(gp2, lp2); gload16(gp3, lp3);
        gload16(gp4, lp4); gload16(gp5, lp5);
        gload16(gp6, lp6); gload16(gp7, lp7);
        gp0 += 32; gp1 += 32; gp2 += 32; gp3 += 32;
        gp4 += 32; gp5 += 32; gp6 += 32; gp7 += 32;
        __syncthreads();

        short8v bh[4], bl[4];
#pragma unroll
        for (int j = 0; j < 4; ++j) {
            int row = wc * 64 + j * 16 + lr;
            int s = (lg ^ ((row >> 1) & 3)) * 8;
            bh[j] = *(const short8v*)&lds[2][row][s];
            bl[j] = *(const short8v*)&lds[3][row][s];
        }
#pragma unroll
        for (int i = 0; i < 4; ++i) {
            int row = wr * 64 + i * 16 + lr;
            int s = (lg ^ ((row >> 1) & 3)) * 8;
            short8v ah = *(const short8v*)&lds[0][row][s];
            short8v al = *(const short8v*)&lds[1][row][s];
#pragma unroll
            for (int j = 0; j < 4; ++j) {
                acc[i][j] = __builtin_amdgcn_mfma_f32_16x16x32_bf16(ah, bh[j], acc[i][j], 0, 0, 0);
                acc[i][j] = __builtin_amdgcn_mfma_f32_16x16x32_bf16(ah, bl[j], acc[i][j], 0, 0, 0);
                acc[i][j] = __builtin_amdgcn_mfma_f32_16x16x32_bf16(al, bh[j], acc[i][j], 0, 0, 0);
            }
        }
    }

    if constexpr (!SCAT) {
        float* Cb = Cout + (size_t)bz * M_ * N_;
#pragma unroll
        for (int i = 0; i < 4; ++i) {
            int mb = m0 + wr * 64 + i * 16 + lg * 4;
#pragma unroll
            for (int j = 0; j < 4; ++j) {
                int nn = n0 + wc * 64 + j * 16 + lr;
#pragma unroll
                for (int r = 0; r < 4; ++r)
                    Cb[(size_t)(mb + r) * N_ + nn] = acc[i][j][r];
            }
        }
    } else {
        // col2im scatter: m = half-res position p, n = (c,ky,kx)
#pragma unroll
        for (int i = 0; i < 4; ++i) {
            int mb = m0 + wr * 64 + i * 16 + lg * 4;
#pragma unroll
            for (int j = 0; j < 4; ++j) {
                int nn = n0 + wc * 64 + j * 16 + lr;
                int c = nn >> 4, ky = (nn >> 2) & 3, kx = nn & 3;
#pragma unroll
                for (int r = 0; r < 4; ++r) {
                    int m = mb + r;
                    int iy = m / WS, ix = m % WS;
                    int y = 2 * iy + ky - 1, x = 2 * ix + kx - 1;
                    if ((unsigned)y < (unsigned)HF && (unsigned)x < (unsigned)WF)
                        atomicAdd(Cout + ((size_t)(bz * CC + c) * HF + y) * WF + x, acc[i][j][r]);
                }
            }
        }
    }
}

// ---- fused double conv_eye + mask + x10: F[l][p] ----
__global__ void fuse_kernel(const float* __restrict__ S, const float* __restrict__ maskadd,
                            float* __restrict__ Sf) {
    int idx = blockIdx.x * 256 + threadIdx.x;
    if (idx >= BN_ * LL * LL) return;
    int p = idx % LL;
    int l = (idx / LL) % LL;
    int n = idx / (LL * LL);
    const float* Sb = S + (size_t)n * LL * LL;
    int Tl = Tswap(l), Tp = Tswap(p);
    float acc = 0.f;
#pragma unroll
    for (int d2 = -1; d2 <= 1; ++d2) {
        int fl = Tl + d2, fp = Tp + d2;
        if (fl < 0 || fl >= LL || fp < 0 || fp >= LL) continue;
        int l2 = Tswap(fl), p2 = Tswap(fp);
#pragma unroll
        for (int d1 = -1; d1 <= 1; ++d1) {
            int l3 = l2 + d1, p3 = p2 + d1;
            if (l3 < 0 || l3 >= LL || p3 < 0 || p3 >= LL) continue;
            acc += Sb[(size_t)l3 * LL + p3];
        }
    }
    Sf[idx] = acc * 10.f + maskadd[n * LL + l];
}

// ---- softmax over l (stride LL) in place ----
__global__ __launch_bounds__(256) void softmax_kernel(float* __restrict__ att) {
    __shared__ float red[8][32];
    int pi = threadIdx.x & 31;
    int lg = threadIdx.x >> 5;
    int p = blockIdx.x * 32 + pi;
    int n = blockIdx.y;
    float* col = att + (size_t)n * LL * LL + p;
    float m = -3e38f;
    for (int l = lg; l < LL; l += 8) m = fmaxf(m, col[(size_t)l * LL]);
    red[lg][pi] = m;
    __syncthreads();
    if (lg == 0) {
#pragma unroll
        for (int q = 1; q < 8; ++q) m = fmaxf(m, red[q][pi]);
        red[0][pi] = m;
    }
    __syncthreads();
    m = red[0][pi];
    __syncthreads();
    float s = 0.f;
    for (int l = lg; l < LL; l += 8) s += __expf(col[(size_t)l * LL] - m);
    red[lg][pi] = s;
    __syncthreads();
    if (lg == 0) {
#pragma unroll
        for (int q = 1; q < 8; ++q) s += red[q][pi];
        red[0][pi] = 1.f / s;
    }
    __syncthreads();
    float inv = red[0][pi];
    for (int l = lg; l < LL; l += 8)
        col[(size_t)l * LL] = __expf(col[(size_t)l * LL] - m) * inv;
}

// ---- transpose + split: attT[p][l] (bf16 hi/lo) from F[l][p] ----
__global__ __launch_bounds__(256) void transpose_split(const float* __restrict__ F,
                                                       unsigned short* __restrict__ Th,
                                                       unsigned short* __restrict__ Tl) {
    __shared__ float tile[32][33];
    int n = blockIdx.z;
    int l0 = blockIdx.y * 32, p0 = blockIdx.x * 32;
    const float* Fb = F + (size_t)n * LL * LL;
    int tx = threadIdx.x & 31, ty = threadIdx.x >> 5;
#pragma unroll
    for (int q = 0; q < 4; ++q)
        tile[ty + q * 8][tx] = Fb[(size_t)(l0 + ty + q * 8) * LL + p0 + tx];
    __syncthreads();
#pragma unroll
    for (int q = 0; q < 4; ++q) {
        int p = p0 + ty + q * 8;
        float v = tile[tx][ty + q * 8];
        unsigned short h = f2bf(v);
        size_t o = ((size_t)n * LL + p) * LL + l0 + tx;
        Th[o] = h;
        Tl[o] = f2bf(v - bf2f(h));
    }
}

// ---- final overlap normalization ----
__global__ void normalize_kernel(float* __restrict__ out) {
    int idx = blockIdx.x * 256 + threadIdx.x;
    if (idx >= BN_ * CC * HF * WF) return;
    int x = idx % WF, y = (idx / WF) % HF;
    float s = ((y == 0 || y == HF - 1) ? 1.f : 0.5f) * ((x == 0 || x == WF - 1) ? 1.f : 0.5f);
    out[idx] *= s;
}

extern "C" void kernel_launch(void* const* d_in, const int* in_sizes, int n_in,
                              void* d_out, int out_size, void* d_ws, size_t ws_size,
                              hipStream_t stream) {
    const float* x       = (const float*)d_in[0];
    const float* context = (const float*)d_in[1];
    const float* mask    = (const float*)d_in[2];

    float* out = (float*)d_out;                                  // [4][96][96][96]
    float* att_region = out + (size_t)BN_ * CC * HF * WF;        // [4][2304][2304] fp32
    unsigned short* Th = (unsigned short*)att_region;            // attT hi (overlay)
    unsigned short* Tl = Th + (size_t)BN_ * LL * LL;             // attT lo

    // workspace (peak 141.7 MB, < proven 142 MB):
    //   [0 .. 63.7MB]  cols_hi/lo, xp_hi/lo  -> later F (84.9MB, to 84.9)
    //   [84.9 .. 141.5] RF_hi/lo
    //   [141.5 ..]      ssum, invn, maskadd
    char* wsb = (char*)d_ws;
    const size_t EK1 = (size_t)BN_ * LL * K1;      // 7,962,624
    const size_t ERF = (size_t)BN_ * J2 * LL;      // 14,155,776
    unsigned short* cols_hi = (unsigned short*)wsb;
    unsigned short* cols_lo = cols_hi + EK1;
    unsigned short* xp_hi   = cols_lo + EK1;
    unsigned short* xp_lo   = xp_hi + EK1;
    float* F = (float*)wsb;                                   // overlays cols/xp after GEMM1
    unsigned short* RF_hi = (unsigned short*)(wsb + 84934656);
    unsigned short* RF_lo = RF_hi + ERF;
    float* ssum    = (float*)(wsb + 141557760);
    float* invn    = ssum + BN_ * HS * WS;
    float* maskadd = invn + BN_ * LL;

    // zero the out region for GEMM2's atomic scatter
    hipMemsetAsync(out, 0, (size_t)BN_ * CC * HF * WF * sizeof(float), stream);

    ssum_kernel<<<(BN_ * HS * WS + 255) / 256, 256, 0, stream>>>(context, ssum);
    invn_kernel<<<(BN_ * LL + 255) / 256, 256, 0, stream>>>(ssum, invn);
    mask_kernel<<<(BN_ * LL + 255) / 256, 256, 0, stream>>>(mask, maskadd);

    im2col_split<<<(int)(EK1 / 256), 256, 0, stream>>>(x, nullptr, xp_hi, xp_lo);
    im2col_split<<<(int)(EK1 / 256), 256, 0, stream>>>(context, invn, cols_hi, cols_lo);

    // GEMM1: S[l][p] (fp32, in d_out att region) = cols . xp^T
    dim3 g1(LL / 128, LL / 128, BN_);
    gemm_split<false><<<g1, 256, 0, stream>>>(cols_hi, cols_lo, xp_hi, xp_lo,
                                              att_region, LL, LL, K1);

    // fuse (reads S from att region) -> F ; softmax in F
    fuse_kernel<<<(int)((size_t)BN_ * LL * LL / 256), 256, 0, stream>>>(att_region, maskadd, F);
    softmax_kernel<<<dim3(LL / 32, BN_), 256, 0, stream>>>(F);

    // transpose+split att -> attT (att region), raw filters
    transpose_split<<<dim3(LL / 32, LL / 32, BN_), 256, 0, stream>>>(F, Th, Tl);
    rf_split<<<(int)(ERF / 256), 256, 0, stream>>>(context, RF_hi, RF_lo);

    // GEMM2: G[p][j] = att^T . RF^T, scattered (col2im) into out via atomics
    dim3 g2(J2 / 128, LL / 128, BN_);
    gemm_split<true><<<g2, 256, 0, stream>>>(Th, Tl, RF_hi, RF_lo, out, LL, J2, LL);

    normalize_kernel<<<(BN_ * CC * HF * WF + 255) / 256, 256, 0, stream>>>(out);

    // final att_score = F -> d_out att region (attT dead after GEMM2)
    hipMemcpyAsync(att_region, F, (size_t)BN_ * LL * LL * sizeof(float),
                   hipMemcpyDeviceToDevice, stream);
}

// Round 3
// 761.638 us; speedup vs baseline: 2.3640x; 1.2033x over previous
//
#include <hip/hip_runtime.h>
#include <stdint.h>

// Problem constants (N,C,H,W)=(4,96,96,96), half-res 48x48
#define BN_ 4
#define CC 96
#define HF 96
#define WF 96
#define HS 48
#define WS 48
#define LL 2304      // HS*WS
#define K1 864       // CC*9  (3x3 patch feature dim)
#define J2 1536      // CC*16 (4x4 raw filter feature dim)
#define NEG10 (-1.0e10f)

typedef __attribute__((ext_vector_type(8))) short short8v;
typedef __attribute__((ext_vector_type(4))) float float4v;

__device__ __forceinline__ int Tswap(int f) { return (f % 48) * 48 + f / 48; }

__device__ __forceinline__ unsigned short f2bf(float f) {
    union { float f; uint32_t u; } v; v.f = f;
    uint32_t u = v.u;
    uint32_t r = (u + 0x7fffu + ((u >> 16) & 1u)) >> 16;
    return (unsigned short)r;
}
__device__ __forceinline__ float bf2f(unsigned short h) {
    union { uint32_t u; float f; } v; v.u = ((uint32_t)h) << 16;
    return v.f;
}

typedef const __attribute__((address_space(1))) uint32_t* gas_ptr;
typedef __attribute__((address_space(3))) uint32_t* las_ptr;
__device__ __forceinline__ void gload16(const void* g, void* l) {
    __builtin_amdgcn_global_load_lds((gas_ptr)g, (las_ptr)l, 16, 0, 0);
}

// ---- channel-sum-of-squares of strided context: ssum[n][i][j] ----
__global__ void ssum_kernel(const float* __restrict__ ctx, float* __restrict__ ssum) {
    int idx = blockIdx.x * 256 + threadIdx.x;
    if (idx >= BN_ * HS * WS) return;
    int j = idx % WS, i = (idx / WS) % HS, n = idx / (WS * HS);
    float s = 0.f;
    for (int c = 0; c < CC; ++c) {
        float v = ctx[((size_t)(n * CC + c) * HF + 2 * i) * WF + 2 * j];
        s += v * v;
    }
    ssum[idx] = s;
}

// ---- invn[n][l] = 1/max(sqrt(sum 3x3 ssum),1e-4) ----
__global__ void invn_kernel(const float* __restrict__ ssum, float* __restrict__ invn) {
    int idx = blockIdx.x * 256 + threadIdx.x;
    if (idx >= BN_ * LL) return;
    int l = idx % LL, n = idx / LL;
    int i0 = l / WS, j0 = l % WS;
    float s = 0.f;
    for (int dy = -1; dy <= 1; ++dy)
        for (int dx = -1; dx <= 1; ++dx) {
            int i = i0 + dy, j = j0 + dx;
            if (i >= 0 && i < HS && j >= 0 && j < WS)
                s += ssum[(n * HS + i) * WS + j];
        }
    invn[idx] = 1.f / fmaxf(sqrtf(s), 1e-4f);
}

// ---- maskadd[n][l] ----
__global__ void mask_kernel(const float* __restrict__ mask, float* __restrict__ maskadd) {
    int idx = blockIdx.x * 256 + threadIdx.x;
    if (idx >= BN_ * LL) return;
    int l = idx % LL, n = idx / LL;
    int i0 = l / WS, j0 = l % WS;
    float s = 0.f;
    for (int dy = -1; dy <= 1; ++dy)
        for (int dx = -1; dx <= 1; ++dx) {
            int i = i0 + dy, j = j0 + dx;
            if (i >= 0 && i < HS && j >= 0 && j < WS)
                s += mask[(size_t)n * HF * WF + (2 * i) * WF + 2 * j];
        }
    maskadd[idx] = (s > 0.f) ? NEG10 : 0.f;
}

// ---- im2col 3x3 (pad 1) of ::2 slice + bf16 hi/lo split; dst [n][l][864] k-major ----
__global__ void im2col_split(const float* __restrict__ src, const float* __restrict__ scale,
                             unsigned short* __restrict__ hi, unsigned short* __restrict__ lo) {
    int idx = blockIdx.x * 256 + threadIdx.x;
    if (idx >= BN_ * LL * K1) return;
    int k = idx % K1;
    int l = (idx / K1) % LL;
    int n = idx / (K1 * LL);
    int c = k / 9, r = k % 9;
    int i = l / WS + r / 3 - 1;
    int j = l % WS + r % 3 - 1;
    float v = 0.f;
    if (i >= 0 && i < HS && j >= 0 && j < WS)
        v = src[((size_t)(n * CC + c) * HF + 2 * i) * WF + 2 * j];
    if (scale) v *= scale[n * LL + l];
    unsigned short h = f2bf(v);
    hi[idx] = h;
    lo[idx] = f2bf(v - bf2f(h));
}

// ---- raw filter, transposed, hi only: RF[n][j][l] ----
__global__ void rf_split(const float* __restrict__ ctx, unsigned short* __restrict__ hi) {
    int idx = blockIdx.x * 256 + threadIdx.x;
    if (idx >= BN_ * J2 * LL) return;
    int l = idx % LL;
    int j = (idx / LL) % J2;
    int n = idx / (LL * J2);
    int c = j >> 4, ky = (j >> 2) & 3, kx = j & 3;
    int y = 2 * (l / WS) + ky - 1;
    int x = 2 * (l % WS) + kx - 1;
    float v = 0.f;
    if (y >= 0 && y < HF && x >= 0 && x < WF)
        v = ctx[((size_t)(n * CC + c) * HF + y) * WF + x];
    hi[idx] = f2bf(v);
}

// ---- split-bf16 MFMA GEMM: C[m][n] = sum_k A[m][k]*B[n][k] ----
// TERMS=3: Ah*Bh + Ah*Bl + Al*Bh (full split). TERMS=2: Ah*Bh + Al*Bh (exact-A x bf16 B).
// OBF: write C as bf16 (ushort), else fp32. Flat 1D grid + bijective XCD chunk swizzle.
template <int TERMS, bool OBF>
__global__ __launch_bounds__(256, 4) void gemm_split(
    const unsigned short* __restrict__ Ah_, const unsigned short* __restrict__ Al_,
    const unsigned short* __restrict__ Bh_, const unsigned short* __restrict__ Bl_,
    void* __restrict__ Cout, int M_, int N_, int K_, int nbx, int nby)
{
    constexpr int NB = (TERMS == 3) ? 4 : 3;
    __shared__ unsigned short lds[NB][128][32];   // Ah, Al, Bh, [Bl]

    int wg = blockIdx.x;
    int wgid = (wg & 7) * (gridDim.x >> 3) + (wg >> 3);   // XCD chunk swizzle (grid%8==0)
    int bx = wgid % nbx;
    int t1 = wgid / nbx;
    int by = t1 % nby;
    int bz = t1 / nby;
    const int m0 = by * 128, n0 = bx * 128;
    const int t = threadIdx.x;

    const size_t sA = (size_t)M_ * K_, sB = (size_t)N_ * K_;
    const unsigned short* Ah = Ah_ + (size_t)bz * sA;
    const unsigned short* Al = Al_ + (size_t)bz * sA;
    const unsigned short* Bh = Bh_ + (size_t)bz * sB;

    // staging: thread t covers LDS row rloc, 16B slot sst; XOR swizzle on k-group.
    const int rloc = t >> 2;
    const int sst = t & 3;
    const int kg = sst ^ ((rloc >> 1) & 3);
    const size_t offA0 = (size_t)(m0 + rloc) * K_ + kg * 8;
    const size_t offA1 = (size_t)(m0 + 64 + rloc) * K_ + kg * 8;
    const size_t offB0 = (size_t)(n0 + rloc) * K_ + kg * 8;
    const size_t offB1 = (size_t)(n0 + 64 + rloc) * K_ + kg * 8;
    const unsigned short* gp0 = Ah + offA0;
    const unsigned short* gp1 = Ah + offA1;
    const unsigned short* gp2 = Al + offA0;
    const unsigned short* gp3 = Al + offA1;
    const unsigned short* gp4 = Bh + offB0;
    const unsigned short* gp5 = Bh + offB1;
    const unsigned short* gp6 = nullptr;
    const unsigned short* gp7 = nullptr;
    unsigned short* lp0 = &lds[0][rloc][sst * 8];
    unsigned short* lp1 = &lds[0][64 + rloc][sst * 8];
    unsigned short* lp2 = &lds[1][rloc][sst * 8];
    unsigned short* lp3 = &lds[1][64 + rloc][sst * 8];
    unsigned short* lp4 = &lds[2][rloc][sst * 8];
    unsigned short* lp5 = &lds[2][64 + rloc][sst * 8];
    unsigned short* lp6 = nullptr;
    unsigned short* lp7 = nullptr;
    if constexpr (TERMS == 3) {
        const unsigned short* Bl = Bl_ + (size_t)bz * sB;
        gp6 = Bl + offB0;
        gp7 = Bl + offB1;
        lp6 = &lds[NB - 1][rloc][sst * 8];
        lp7 = &lds[NB - 1][64 + rloc][sst * 8];
    }

    const int lane = t & 63;
    const int w = t >> 6, wr = w >> 1, wc = w & 1;
    const int lr = lane & 15, lg = lane >> 4;

    float4v acc[4][4] = {};

    for (int kt = 0; kt < K_; kt += 32) {
        __syncthreads();
        gload16(gp0, lp0); gload16(gp1, lp1);
        gload16(gp2, lp2); gload16(gp3, lp3);
        gload16(gp4, lp4); gload16(gp5, lp5);
        if constexpr (TERMS == 3) { gload16(gp6, lp6); gload16(gp7, lp7); }
        gp0 += 32; gp1 += 32; gp2 += 32; gp3 += 32; gp4 += 32; gp5 += 32;
        if constexpr (TERMS == 3) { gp6 += 32; gp7 += 32; }
        __syncthreads();

        short8v bh[4], bl[4];
#pragma unroll
        for (int j = 0; j < 4; ++j) {
            int row = wc * 64 + j * 16 + lr;
            int s = (lg ^ ((row >> 1) & 3)) * 8;
            bh[j] = *(const short8v*)&lds[2][row][s];
            if constexpr (TERMS == 3) bl[j] = *(const short8v*)&lds[NB - 1][row][s];
        }
#pragma unroll
        for (int i = 0; i < 4; ++i) {
            int row = wr * 64 + i * 16 + lr;
            int s = (lg ^ ((row >> 1) & 3)) * 8;
            short8v ah = *(const short8v*)&lds[0][row][s];
            short8v al = *(const short8v*)&lds[1][row][s];
#pragma unroll
            for (int j = 0; j < 4; ++j) {
                acc[i][j] = __builtin_amdgcn_mfma_f32_16x16x32_bf16(ah, bh[j], acc[i][j], 0, 0, 0);
                if constexpr (TERMS == 3)
                    acc[i][j] = __builtin_amdgcn_mfma_f32_16x16x32_bf16(ah, bl[j], acc[i][j], 0, 0, 0);
                acc[i][j] = __builtin_amdgcn_mfma_f32_16x16x32_bf16(al, bh[j], acc[i][j], 0, 0, 0);
            }
        }
    }

    if constexpr (!OBF) {
        float* Cb = (float*)Cout + (size_t)bz * M_ * N_;
#pragma unroll
        for (int i = 0; i < 4; ++i) {
            int mb = m0 + wr * 64 + i * 16 + lg * 4;
#pragma unroll
            for (int j = 0; j < 4; ++j) {
                int nn = n0 + wc * 64 + j * 16 + lr;
#pragma unroll
                for (int r = 0; r < 4; ++r)
                    Cb[(size_t)(mb + r) * N_ + nn] = acc[i][j][r];
            }
        }
    } else {
        unsigned short* Gb = (unsigned short*)Cout + (size_t)bz * M_ * N_;
#pragma unroll
        for (int i = 0; i < 4; ++i) {
            int mb = m0 + wr * 64 + i * 16 + lg * 4;
#pragma unroll
            for (int j = 0; j < 4; ++j) {
                int nn = n0 + wc * 64 + j * 16 + lr;
#pragma unroll
                for (int r = 0; r < 4; ++r)
                    Gb[(size_t)(mb + r) * N_ + nn] = f2bf(acc[i][j][r]);
            }
        }
    }
}

// ---- fused double conv_eye + mask + x10, XCD-swizzled: F[l][p] ----
__global__ void fuse_kernel(const float* __restrict__ S, const float* __restrict__ maskadd,
                            float* __restrict__ Sf) {
    int wg = blockIdx.x;
    int wgid = (wg & 7) * (gridDim.x >> 3) + (wg >> 3);
    int idx = wgid * 256 + threadIdx.x;
    int p = idx % LL;
    int l = (idx / LL) % LL;
    int n = idx / (LL * LL);
    const float* Sb = S + (size_t)n * LL * LL;
    int Tl = Tswap(l), Tp = Tswap(p);
    float acc = 0.f;
#pragma unroll
    for (int d2 = -1; d2 <= 1; ++d2) {
        int fl = Tl + d2, fp = Tp + d2;
        if (fl < 0 || fl >= LL || fp < 0 || fp >= LL) continue;
        int l2 = Tswap(fl), p2 = Tswap(fp);
#pragma unroll
        for (int d1 = -1; d1 <= 1; ++d1) {
            int l3 = l2 + d1, p3 = p2 + d1;
            if (l3 < 0 || l3 >= LL || p3 < 0 || p3 >= LL) continue;
            acc += Sb[(size_t)l3 * LL + p3];
        }
    }
    Sf[idx] = acc * 10.f + maskadd[n * LL + l];
}

// ---- softmax over l (stride LL) in place ----
__global__ __launch_bounds__(256) void softmax_kernel(float* __restrict__ att) {
    __shared__ float red[8][32];
    int pi = threadIdx.x & 31;
    int lg = threadIdx.x >> 5;
    int p = blockIdx.x * 32 + pi;
    int n = blockIdx.y;
    float* col = att + (size_t)n * LL * LL + p;
    float m = -3e38f;
    for (int l = lg; l < LL; l += 8) m = fmaxf(m, col[(size_t)l * LL]);
    red[lg][pi] = m;
    __syncthreads();
    if (lg == 0) {
#pragma unroll
        for (int q = 1; q < 8; ++q) m = fmaxf(m, red[q][pi]);
        red[0][pi] = m;
    }
    __syncthreads();
    m = red[0][pi];
    __syncthreads();
    float s = 0.f;
    for (int l = lg; l < LL; l += 8) s += __expf(col[(size_t)l * LL] - m);
    red[lg][pi] = s;
    __syncthreads();
    if (lg == 0) {
#pragma unroll
        for (int q = 1; q < 8; ++q) s += red[q][pi];
        red[0][pi] = 1.f / s;
    }
    __syncthreads();
    float inv = red[0][pi];
    for (int l = lg; l < LL; l += 8)
        col[(size_t)l * LL] = __expf(col[(size_t)l * LL] - m) * inv;
}

// ---- transpose + split: attT[p][l] (bf16 hi/lo) from att[l][p] ----
__global__ __launch_bounds__(256) void transpose_split(const float* __restrict__ F,
                                                       unsigned short* __restrict__ Th,
                                                       unsigned short* __restrict__ Tl) {
    __shared__ float tile[32][33];
    int n = blockIdx.z;
    int l0 = blockIdx.y * 32, p0 = blockIdx.x * 32;
    const float* Fb = F + (size_t)n * LL * LL;
    int tx = threadIdx.x & 31, ty = threadIdx.x >> 5;
#pragma unroll
    for (int q = 0; q < 4; ++q)
        tile[ty + q * 8][tx] = Fb[(size_t)(l0 + ty + q * 8) * LL + p0 + tx];
    __syncthreads();
#pragma unroll
    for (int q = 0; q < 4; ++q) {
        int p = p0 + ty + q * 8;
        float v = tile[tx][ty + q * 8];
        unsigned short h = f2bf(v);
        size_t o = ((size_t)n * LL + p) * LL + l0 + tx;
        Th[o] = h;
        Tl[o] = f2bf(v - bf2f(h));
    }
}

// ---- col2im gather from bf16 G[p][j] + overlap division ----
__global__ void col2im_kernel(const unsigned short* __restrict__ G, float* __restrict__ out) {
    int idx = blockIdx.x * 256 + threadIdx.x;
    if (idx >= BN_ * CC * HF * WF) return;
    int x = idx % WF;
    int y = (idx / WF) % HF;
    int c = (idx / (WF * HF)) % CC;
    int n = idx / (WF * HF * CC);
    const unsigned short* Gb = G + (size_t)n * LL * J2;
    float acc = 0.f;
#pragma unroll
    for (int ky = 0; ky < 4; ++ky) {
        int ynum = y + 1 - ky;
        if (ynum & 1) continue;
        int iy = ynum >> 1;
        if (iy < 0 || iy >= HS) continue;
#pragma unroll
        for (int kx = 0; kx < 4; ++kx) {
            int xnum = x + 1 - kx;
            if (xnum & 1) continue;
            int ix = xnum >> 1;
            if (ix < 0 || ix >= WS) continue;
            acc += bf2f(Gb[(size_t)(iy * WS + ix) * J2 + c * 16 + ky * 4 + kx]);
        }
    }
    float cy = (y == 0 || y == HF - 1) ? 1.f : 2.f;
    float cx = (x == 0 || x == WF - 1) ? 1.f : 2.f;
    out[idx] = acc / (cy * cx);
}

extern "C" void kernel_launch(void* const* d_in, const int* in_sizes, int n_in,
                              void* d_out, int out_size, void* d_ws, size_t ws_size,
                              hipStream_t stream) {
    const float* x       = (const float*)d_in[0];
    const float* context = (const float*)d_in[1];
    const float* mask    = (const float*)d_in[2];

    float* out = (float*)d_out;                                  // [4][96][96][96]
    float* att_region = out + (size_t)BN_ * CC * HF * WF;        // [4][2304][2304] fp32 (final att)

    // workspace layout (bytes); proven ws_size >= 148,709,376 (round 1).
    //   phase 1: cols/xp splits @0..63,700,992 ; S fp32 @63,700,992..148,635,648
    //   phase 2 (after fuse, S/cols dead): Th/Tl @0..84,934,656 ;
    //            RF_hi @84,934,656..113,246,208 ; G bf16 @113,246,208..141,557,760
    //   maskadd @148,635,648 (survives until fuse); ssum/invn inside future-S (dead early)
    char* wsb = (char*)d_ws;
    const size_t EK1 = (size_t)BN_ * LL * K1;      // 7,962,624
    const size_t ERF = (size_t)BN_ * J2 * LL;      // 14,155,776
    unsigned short* cols_hi = (unsigned short*)wsb;
    unsigned short* cols_lo = cols_hi + EK1;
    unsigned short* xp_hi   = cols_lo + EK1;
    unsigned short* xp_lo   = xp_hi + EK1;
    float* S = (float*)(wsb + 63700992);
    unsigned short* Th    = (unsigned short*)wsb;                 // after fuse
    unsigned short* Tl    = Th + (size_t)BN_ * LL * LL;
    unsigned short* RF_hi = (unsigned short*)(wsb + 84934656);
    unsigned short* G     = (unsigned short*)(wsb + 113246208);
    float* ssum    = (float*)(wsb + 63700992);                    // dead before S written
    float* invn    = ssum + BN_ * HS * WS;
    float* maskadd = (float*)(wsb + 148635648);

    ssum_kernel<<<(BN_ * HS * WS + 255) / 256, 256, 0, stream>>>(context, ssum);
    invn_kernel<<<(BN_ * LL + 255) / 256, 256, 0, stream>>>(ssum, invn);
    mask_kernel<<<(BN_ * LL + 255) / 256, 256, 0, stream>>>(mask, maskadd);

    im2col_split<<<(int)(EK1 / 256), 256, 0, stream>>>(x, nullptr, xp_hi, xp_lo);
    im2col_split<<<(int)(EK1 / 256), 256, 0, stream>>>(context, invn, cols_hi, cols_lo);

    // GEMM1 (3-term split): S[l][p] = cols . xp^T  (fp32 into ws)
    gemm_split<3, false><<<(LL / 128) * (LL / 128) * BN_, 256, 0, stream>>>(
        cols_hi, cols_lo, xp_hi, xp_lo, S, LL, LL, K1, LL / 128, LL / 128);

    // fuse (both conv_eye passes) + mask + x10 -> att_region (d_out)
    fuse_kernel<<<(int)((size_t)BN_ * LL * LL / 256), 256, 0, stream>>>(S, maskadd, att_region);

    // softmax over l, in place -> final fp32 att output
    softmax_kernel<<<dim3(LL / 32, BN_), 256, 0, stream>>>(att_region);

    // att^T bf16 hi/lo into ws; raw filters (hi only)
    transpose_split<<<dim3(LL / 32, LL / 32, BN_), 256, 0, stream>>>(att_region, Th, Tl);
    rf_split<<<(int)(ERF / 256), 256, 0, stream>>>(context, RF_hi);

    // GEMM2 (2-term: exact-att x bf16 RF): G[p][j] bf16
    gemm_split<2, true><<<(J2 / 128) * (LL / 128) * BN_, 256, 0, stream>>>(
        Th, Tl, RF_hi, nullptr, G, LL, J2, LL, J2 / 128, LL / 128);

    // col2im gather + overlap normalization -> out
    col2im_kernel<<<(BN_ * CC * HF * WF + 255) / 256, 256, 0, stream>>>(G, out);
}

// Round 4
// 567.310 us; speedup vs baseline: 3.1738x; 1.3425x over previous
//
#include <hip/hip_runtime.h>
#include <stdint.h>

// Problem constants (N,C,H,W)=(4,96,96,96), half-res 48x48
#define BN_ 4
#define CC 96
#define HF 96
#define WF 96
#define HS 48
#define WS 48
#define LL 2304      // HS*WS
#define K1 864       // CC*9  (3x3 patch feature dim)
#define J2 1536      // CC*16 (4x4 raw filter feature dim)
#define NEG10 (-1.0e10f)

typedef __attribute__((ext_vector_type(8))) short short8v;
typedef __attribute__((ext_vector_type(4))) float float4v;

__device__ __forceinline__ int Tswap(int f) { return (f % 48) * 48 + f / 48; }

__device__ __forceinline__ unsigned short f2bf(float f) {
    union { float f; uint32_t u; } v; v.f = f;
    uint32_t u = v.u;
    uint32_t r = (u + 0x7fffu + ((u >> 16) & 1u)) >> 16;
    return (unsigned short)r;
}
__device__ __forceinline__ float bf2f(unsigned short h) {
    union { uint32_t u; float f; } v; v.u = ((uint32_t)h) << 16;
    return v.f;
}

typedef const __attribute__((address_space(1))) uint32_t* gas_ptr;
typedef __attribute__((address_space(3))) uint32_t* las_ptr;
__device__ __forceinline__ void gload16(const void* g, void* l) {
    __builtin_amdgcn_global_load_lds((gas_ptr)g, (las_ptr)l, 16, 0, 0);
}

// ---- channel-sum-of-squares of strided context: ssum[n][i][j] ----
__global__ void ssum_kernel(const float* __restrict__ ctx, float* __restrict__ ssum) {
    int idx = blockIdx.x * 256 + threadIdx.x;
    if (idx >= BN_ * HS * WS) return;
    int j = idx % WS, i = (idx / WS) % HS, n = idx / (WS * HS);
    float s = 0.f;
    for (int c = 0; c < CC; ++c) {
        float v = ctx[((size_t)(n * CC + c) * HF + 2 * i) * WF + 2 * j];
        s += v * v;
    }
    ssum[idx] = s;
}

// ---- invn[n][l] = 1/max(sqrt(sum 3x3 ssum),1e-4) ----
__global__ void invn_kernel(const float* __restrict__ ssum, float* __restrict__ invn) {
    int idx = blockIdx.x * 256 + threadIdx.x;
    if (idx >= BN_ * LL) return;
    int l = idx % LL, n = idx / LL;
    int i0 = l / WS, j0 = l % WS;
    float s = 0.f;
    for (int dy = -1; dy <= 1; ++dy)
        for (int dx = -1; dx <= 1; ++dx) {
            int i = i0 + dy, j = j0 + dx;
            if (i >= 0 && i < HS && j >= 0 && j < WS)
                s += ssum[(n * HS + i) * WS + j];
        }
    invn[idx] = 1.f / fmaxf(sqrtf(s), 1e-4f);
}

// ---- maskadd[n][l] ----
__global__ void mask_kernel(const float* __restrict__ mask, float* __restrict__ maskadd) {
    int idx = blockIdx.x * 256 + threadIdx.x;
    if (idx >= BN_ * LL) return;
    int l = idx % LL, n = idx / LL;
    int i0 = l / WS, j0 = l % WS;
    float s = 0.f;
    for (int dy = -1; dy <= 1; ++dy)
        for (int dx = -1; dx <= 1; ++dx) {
            int i = i0 + dy, j = j0 + dx;
            if (i >= 0 && i < HS && j >= 0 && j < WS)
                s += mask[(size_t)n * HF * WF + (2 * i) * WF + 2 * j];
        }
    maskadd[idx] = (s > 0.f) ? NEG10 : 0.f;
}

// ---- im2col 3x3 (pad 1) of ::2 slice + bf16 hi/lo split; dst [n][l][864] k-major ----
__global__ void im2col_split(const float* __restrict__ src, const float* __restrict__ scale,
                             unsigned short* __restrict__ hi, unsigned short* __restrict__ lo) {
    int idx = blockIdx.x * 256 + threadIdx.x;
    if (idx >= BN_ * LL * K1) return;
    int k = idx % K1;
    int l = (idx / K1) % LL;
    int n = idx / (K1 * LL);
    int c = k / 9, r = k % 9;
    int i = l / WS + r / 3 - 1;
    int j = l % WS + r % 3 - 1;
    float v = 0.f;
    if (i >= 0 && i < HS && j >= 0 && j < WS)
        v = src[((size_t)(n * CC + c) * HF + 2 * i) * WF + 2 * j];
    if (scale) v *= scale[n * LL + l];
    unsigned short h = f2bf(v);
    hi[idx] = h;
    lo[idx] = f2bf(v - bf2f(h));
}

// ---- raw filter, transposed, hi only: RF[n][j][l] ----
__global__ void rf_split(const float* __restrict__ ctx, unsigned short* __restrict__ hi) {
    int idx = blockIdx.x * 256 + threadIdx.x;
    if (idx >= BN_ * J2 * LL) return;
    int l = idx % LL;
    int j = (idx / LL) % J2;
    int n = idx / (LL * J2);
    int c = j >> 4, ky = (j >> 2) & 3, kx = j & 3;
    int y = 2 * (l / WS) + ky - 1;
    int x = 2 * (l % WS) + kx - 1;
    float v = 0.f;
    if (y >= 0 && y < HF && x >= 0 && x < WF)
        v = ctx[((size_t)(n * CC + c) * HF + y) * WF + x];
    hi[idx] = f2bf(v);
}

// ---- split-bf16 MFMA GEMM: C[m][n] = sum_k A[m][k]*B[n][k] ----
// TERMS=3: Ah*Bh + Ah*Bl + Al*Bh. TERMS=2: Ah*Bh + Al*Bh.
// OBF: write C as bf16, else fp32. Flat 1D grid + bijective XCD chunk swizzle.
template <int TERMS, bool OBF>
__global__ __launch_bounds__(256, 4) void gemm_split(
    const unsigned short* __restrict__ Ah_, const unsigned short* __restrict__ Al_,
    const unsigned short* __restrict__ Bh_, const unsigned short* __restrict__ Bl_,
    void* __restrict__ Cout, int M_, int N_, int K_, int nbx, int nby)
{
    constexpr int NB = (TERMS == 3) ? 4 : 3;
    __shared__ unsigned short lds[NB][128][32];   // Ah, Al, Bh, [Bl]

    int wg = blockIdx.x;
    int wgid = (wg & 7) * (gridDim.x >> 3) + (wg >> 3);   // XCD chunk swizzle (grid%8==0)
    int bx = wgid % nbx;
    int t1 = wgid / nbx;
    int by = t1 % nby;
    int bz = t1 / nby;
    const int m0 = by * 128, n0 = bx * 128;
    const int t = threadIdx.x;

    const size_t sA = (size_t)M_ * K_, sB = (size_t)N_ * K_;
    const unsigned short* Ah = Ah_ + (size_t)bz * sA;
    const unsigned short* Al = Al_ + (size_t)bz * sA;
    const unsigned short* Bh = Bh_ + (size_t)bz * sB;

    const int rloc = t >> 2;
    const int sst = t & 3;
    const int kg = sst ^ ((rloc >> 1) & 3);
    const size_t offA0 = (size_t)(m0 + rloc) * K_ + kg * 8;
    const size_t offA1 = (size_t)(m0 + 64 + rloc) * K_ + kg * 8;
    const size_t offB0 = (size_t)(n0 + rloc) * K_ + kg * 8;
    const size_t offB1 = (size_t)(n0 + 64 + rloc) * K_ + kg * 8;
    const unsigned short* gp0 = Ah + offA0;
    const unsigned short* gp1 = Ah + offA1;
    const unsigned short* gp2 = Al + offA0;
    const unsigned short* gp3 = Al + offA1;
    const unsigned short* gp4 = Bh + offB0;
    const unsigned short* gp5 = Bh + offB1;
    const unsigned short* gp6 = nullptr;
    const unsigned short* gp7 = nullptr;
    unsigned short* lp0 = &lds[0][rloc][sst * 8];
    unsigned short* lp1 = &lds[0][64 + rloc][sst * 8];
    unsigned short* lp2 = &lds[1][rloc][sst * 8];
    unsigned short* lp3 = &lds[1][64 + rloc][sst * 8];
    unsigned short* lp4 = &lds[2][rloc][sst * 8];
    unsigned short* lp5 = &lds[2][64 + rloc][sst * 8];
    unsigned short* lp6 = nullptr;
    unsigned short* lp7 = nullptr;
    if constexpr (TERMS == 3) {
        const unsigned short* Bl = Bl_ + (size_t)bz * sB;
        gp6 = Bl + offB0;
        gp7 = Bl + offB1;
        lp6 = &lds[NB - 1][rloc][sst * 8];
        lp7 = &lds[NB - 1][64 + rloc][sst * 8];
    }

    const int lane = t & 63;
    const int w = t >> 6, wr = w >> 1, wc = w & 1;
    const int lr = lane & 15, lg = lane >> 4;

    float4v acc[4][4] = {};

    for (int kt = 0; kt < K_; kt += 32) {
        __syncthreads();
        gload16(gp0, lp0); gload16(gp1, lp1);
        gload16(gp2, lp2); gload16(gp3, lp3);
        gload16(gp4, lp4); gload16(gp5, lp5);
        if constexpr (TERMS == 3) { gload16(gp6, lp6); gload16(gp7, lp7); }
        gp0 += 32; gp1 += 32; gp2 += 32; gp3 += 32; gp4 += 32; gp5 += 32;
        if constexpr (TERMS == 3) { gp6 += 32; gp7 += 32; }
        __syncthreads();

        short8v bh[4], bl[4];
#pragma unroll
        for (int j = 0; j < 4; ++j) {
            int row = wc * 64 + j * 16 + lr;
            int s = (lg ^ ((row >> 1) & 3)) * 8;
            bh[j] = *(const short8v*)&lds[2][row][s];
            if constexpr (TERMS == 3) bl[j] = *(const short8v*)&lds[NB - 1][row][s];
        }
#pragma unroll
        for (int i = 0; i < 4; ++i) {
            int row = wr * 64 + i * 16 + lr;
            int s = (lg ^ ((row >> 1) & 3)) * 8;
            short8v ah = *(const short8v*)&lds[0][row][s];
            short8v al = *(const short8v*)&lds[1][row][s];
#pragma unroll
            for (int j = 0; j < 4; ++j) {
                acc[i][j] = __builtin_amdgcn_mfma_f32_16x16x32_bf16(ah, bh[j], acc[i][j], 0, 0, 0);
                if constexpr (TERMS == 3)
                    acc[i][j] = __builtin_amdgcn_mfma_f32_16x16x32_bf16(ah, bl[j], acc[i][j], 0, 0, 0);
                acc[i][j] = __builtin_amdgcn_mfma_f32_16x16x32_bf16(al, bh[j], acc[i][j], 0, 0, 0);
            }
        }
    }

    if constexpr (!OBF) {
        float* Cb = (float*)Cout + (size_t)bz * M_ * N_;
#pragma unroll
        for (int i = 0; i < 4; ++i) {
            int mb = m0 + wr * 64 + i * 16 + lg * 4;
#pragma unroll
            for (int j = 0; j < 4; ++j) {
                int nn = n0 + wc * 64 + j * 16 + lr;
#pragma unroll
                for (int r = 0; r < 4; ++r)
                    Cb[(size_t)(mb + r) * N_ + nn] = acc[i][j][r];
            }
        }
    } else {
        unsigned short* Gb = (unsigned short*)Cout + (size_t)bz * M_ * N_;
#pragma unroll
        for (int i = 0; i < 4; ++i) {
            int mb = m0 + wr * 64 + i * 16 + lg * 4;
#pragma unroll
            for (int j = 0; j < 4; ++j) {
                int nn = n0 + wc * 64 + j * 16 + lr;
#pragma unroll
                for (int r = 0; r < 4; ++r)
                    Gb[(size_t)(mb + r) * N_ + nn] = f2bf(acc[i][j][r]);
            }
        }
    }
}

// ---- fused double conv_eye + mask + x10, XCD-swizzled: F[l][p] ----
__global__ void fuse_kernel(const float* __restrict__ S, const float* __restrict__ maskadd,
                            float* __restrict__ Sf) {
    int wg = blockIdx.x;
    int wgid = (wg & 7) * (gridDim.x >> 3) + (wg >> 3);
    int idx = wgid * 256 + threadIdx.x;
    int p = idx % LL;
    int l = (idx / LL) % LL;
    int n = idx / (LL * LL);
    const float* Sb = S + (size_t)n * LL * LL;
    int Tl = Tswap(l), Tp = Tswap(p);
    float acc = 0.f;
#pragma unroll
    for (int d2 = -1; d2 <= 1; ++d2) {
        int fl = Tl + d2, fp = Tp + d2;
        if (fl < 0 || fl >= LL || fp < 0 || fp >= LL) continue;
        int l2 = Tswap(fl), p2 = Tswap(fp);
#pragma unroll
        for (int d1 = -1; d1 <= 1; ++d1) {
            int l3 = l2 + d1, p3 = p2 + d1;
            if (l3 < 0 || l3 >= LL || p3 < 0 || p3 >= LL) continue;
            acc += Sb[(size_t)l3 * LL + p3];
        }
    }
    Sf[idx] = acc * 10.f + maskadd[n * LL + l];
}

// ---- column-wise online softmax stats over F[l][p]: partial (m,s) per l-split ----
// grid (36 p-blocks, 8 l-splits, 4 n), block 256 = 64 p x 4 l-rows
__global__ __launch_bounds__(256) void colstat_kernel(const float* __restrict__ F,
                                                      float* __restrict__ pm,
                                                      float* __restrict__ ps) {
    __shared__ float ms[4][64], ss[4][64];
    int pb = blockIdx.x, lsp = blockIdx.y, n = blockIdx.z;
    int tx = threadIdx.x & 63;
    int ty = threadIdx.x >> 6;
    int p = pb * 64 + tx;
    const float* Fb = F + (size_t)n * LL * LL;
    float m = -3e38f, s = 0.f;
    int l_end = (lsp + 1) * 288;
    for (int l = lsp * 288 + ty; l < l_end; l += 4) {
        float v = Fb[(size_t)l * LL + p];
        float mm = fmaxf(m, v);
        s = s * __expf(m - mm) + __expf(v - mm);
        m = mm;
    }
    ms[ty][tx] = m; ss[ty][tx] = s;
    __syncthreads();
    if (ty == 0) {
#pragma unroll
        for (int q = 1; q < 4; ++q) {
            float m2 = ms[q][tx], s2 = ss[q][tx];
            float mm = fmaxf(m, m2);
            s = s * __expf(m - mm) + s2 * __expf(m2 - mm);
            m = mm;
        }
        pm[((size_t)n * 8 + lsp) * LL + p] = m;
        ps[((size_t)n * 8 + lsp) * LL + p] = s;
    }
}

// ---- merge 8 partials -> mstat[p], sinv[p] ----
__global__ void mergestat_kernel(const float* __restrict__ pm, const float* __restrict__ ps,
                                 float* __restrict__ mstat, float* __restrict__ sinv) {
    int idx = blockIdx.x * 256 + threadIdx.x;
    if (idx >= BN_ * LL) return;
    int n = idx / LL, p = idx % LL;
    float m = -3e38f, s = 0.f;
#pragma unroll
    for (int q = 0; q < 8; ++q) {
        float m2 = pm[((size_t)n * 8 + q) * LL + p];
        float s2 = ps[((size_t)n * 8 + q) * LL + p];
        float mm = fmaxf(m, m2);
        s = s * __expf(m - mm) + s2 * __expf(m2 - mm);
        m = mm;
    }
    mstat[idx] = m;
    sinv[idx] = 1.f / s;
}

// ---- finish: att = exp(F-m)*sinv in place; emit transposed bf16 hi/lo attT[p][l] ----
__global__ __launch_bounds__(256) void finish_kernel(float* __restrict__ F,
                                                     const float* __restrict__ mstat,
                                                     const float* __restrict__ sinv,
                                                     unsigned short* __restrict__ Th,
                                                     unsigned short* __restrict__ Tl) {
    __shared__ float tile[32][33];
    int n = blockIdx.z;
    int l0 = blockIdx.y * 32, p0 = blockIdx.x * 32;
    float* Fb = F + (size_t)n * LL * LL;
    int tx = threadIdx.x & 31, ty = threadIdx.x >> 5;
    float m = mstat[n * LL + p0 + tx];
    float si = sinv[n * LL + p0 + tx];
#pragma unroll
    for (int q = 0; q < 4; ++q) {
        int l = l0 + ty + q * 8;
        size_t o = (size_t)l * LL + p0 + tx;
        float e = __expf(Fb[o] - m) * si;
        Fb[o] = e;                 // in-place: F -> att (same element)
        tile[ty + q * 8][tx] = e;  // tile[li][pi]
    }
    __syncthreads();
#pragma unroll
    for (int q = 0; q < 4; ++q) {
        int p = p0 + ty + q * 8;
        float v = tile[tx][ty + q * 8];   // (p, l0+tx)
        unsigned short h = f2bf(v);
        size_t o = ((size_t)n * LL + p) * LL + l0 + tx;
        Th[o] = h;
        Tl[o] = f2bf(v - bf2f(h));
    }
}

// ---- col2im gather from bf16 G[p][j] + overlap division ----
__global__ void col2im_kernel(const unsigned short* __restrict__ G, float* __restrict__ out) {
    int idx = blockIdx.x * 256 + threadIdx.x;
    if (idx >= BN_ * CC * HF * WF) return;
    int x = idx % WF;
    int y = (idx / WF) % HF;
    int c = (idx / (WF * HF)) % CC;
    int n = idx / (WF * HF * CC);
    const unsigned short* Gb = G + (size_t)n * LL * J2;
    float acc = 0.f;
#pragma unroll
    for (int ky = 0; ky < 4; ++ky) {
        int ynum = y + 1 - ky;
        if (ynum & 1) continue;
        int iy = ynum >> 1;
        if (iy < 0 || iy >= HS) continue;
#pragma unroll
        for (int kx = 0; kx < 4; ++kx) {
            int xnum = x + 1 - kx;
            if (xnum & 1) continue;
            int ix = xnum >> 1;
            if (ix < 0 || ix >= WS) continue;
            acc += bf2f(Gb[(size_t)(iy * WS + ix) * J2 + c * 16 + ky * 4 + kx]);
        }
    }
    float cy = (y == 0 || y == HF - 1) ? 1.f : 2.f;
    float cx = (x == 0 || x == WF - 1) ? 1.f : 2.f;
    out[idx] = acc / (cy * cx);
}

extern "C" void kernel_launch(void* const* d_in, const int* in_sizes, int n_in,
                              void* d_out, int out_size, void* d_ws, size_t ws_size,
                              hipStream_t stream) {
    const float* x       = (const float*)d_in[0];
    const float* context = (const float*)d_in[1];
    const float* mask    = (const float*)d_in[2];

    float* out = (float*)d_out;                                  // [4][96][96][96]
    float* att_region = out + (size_t)BN_ * CC * HF * WF;        // [4][2304][2304] fp32

    // workspace layout (bytes); proven ws_size >= 148,672,512.
    //   phase 1: cols/xp splits @0..63,700,992 ; S fp32 @63,700,992..148,635,648
    //   phase 2 (after fuse; S/cols dead): Th/Tl @0..84,934,656 ;
    //            RF_hi @84,934,656..113,246,208 ; G bf16 @113,246,208..141,557,760 ;
    //            softmax stats @141,557,760 (dead S tail) ; maskadd @148,635,648
    char* wsb = (char*)d_ws;
    const size_t EK1 = (size_t)BN_ * LL * K1;      // 7,962,624
    const size_t ERF = (size_t)BN_ * J2 * LL;      // 14,155,776
    unsigned short* cols_hi = (unsigned short*)wsb;
    unsigned short* cols_lo = cols_hi + EK1;
    unsigned short* xp_hi   = cols_lo + EK1;
    unsigned short* xp_lo   = xp_hi + EK1;
    float* S = (float*)(wsb + 63700992);
    unsigned short* Th    = (unsigned short*)wsb;                 // after fuse
    unsigned short* Tl    = Th + (size_t)BN_ * LL * LL;
    unsigned short* RF_hi = (unsigned short*)(wsb + 84934656);
    unsigned short* G     = (unsigned short*)(wsb + 113246208);
    float* pm    = (float*)(wsb + 141557760);                     // [4][8][2304]
    float* ps    = pm + (size_t)BN_ * 8 * LL;
    float* mstat = ps + (size_t)BN_ * 8 * LL;                     // [4][2304]
    float* sinv  = mstat + BN_ * LL;
    float* ssum    = (float*)(wsb + 63700992);                    // dead before S written
    float* invn    = ssum + BN_ * HS * WS;
    float* maskadd = (float*)(wsb + 148635648);

    ssum_kernel<<<(BN_ * HS * WS + 255) / 256, 256, 0, stream>>>(context, ssum);
    invn_kernel<<<(BN_ * LL + 255) / 256, 256, 0, stream>>>(ssum, invn);
    mask_kernel<<<(BN_ * LL + 255) / 256, 256, 0, stream>>>(mask, maskadd);

    im2col_split<<<(int)(EK1 / 256), 256, 0, stream>>>(x, nullptr, xp_hi, xp_lo);
    im2col_split<<<(int)(EK1 / 256), 256, 0, stream>>>(context, invn, cols_hi, cols_lo);

    // GEMM1 (3-term split): S[l][p] = cols . xp^T  (fp32 into ws)
    gemm_split<3, false><<<(LL / 128) * (LL / 128) * BN_, 256, 0, stream>>>(
        cols_hi, cols_lo, xp_hi, xp_lo, S, LL, LL, K1, LL / 128, LL / 128);

    // fuse (both conv_eye passes) + mask + x10 -> att_region (d_out)
    fuse_kernel<<<(int)((size_t)BN_ * LL * LL / 256), 256, 0, stream>>>(S, maskadd, att_region);

    // softmax over l: coalesced column stats + in-place finish (also emits attT bf16)
    colstat_kernel<<<dim3(LL / 64, 8, BN_), 256, 0, stream>>>(att_region, pm, ps);
    mergestat_kernel<<<(BN_ * LL + 255) / 256, 256, 0, stream>>>(pm, ps, mstat, sinv);
    finish_kernel<<<dim3(LL / 32, LL / 32, BN_), 256, 0, stream>>>(att_region, mstat, sinv, Th, Tl);

    // raw filters (hi only)
    rf_split<<<(int)(ERF / 256), 256, 0, stream>>>(context, RF_hi);

    // GEMM2 (2-term: exact-att x bf16 RF): G[p][j] bf16
    gemm_split<2, true><<<(J2 / 128) * (LL / 128) * BN_, 256, 0, stream>>>(
        Th, Tl, RF_hi, nullptr, G, LL, J2, LL, J2 / 128, LL / 128);

    // col2im gather + overlap normalization -> out
    col2im_kernel<<<(BN_ * CC * HF * WF + 255) / 256, 256, 0, stream>>>(G, out);
}